// Round 2
// baseline (100.137 us; speedup 1.0000x reference)
//
#include <hip/hip_runtime.h>
#include <math.h>

#define BLOCK 256
#define VEC   4
#define POS_PER_BLOCK (BLOCK * VEC)   // 1024 positions per block

__global__ __launch_bounds__(BLOCK) void yolo_decode_kernel(
    const float* __restrict__ x,
    const float* __restrict__ anchors,
    float* __restrict__ out,
    int total)
{
    constexpr int G   = 152;
    constexpr int GG  = G * G;        // 23104 (divisible by 4)
    constexpr int NUM = 3;
    constexpr int CPA = 14;           // channels per anchor
    constexpr float STRIDE = 4.0f;    // 608 / 152

    // 1024 positions x 15 floats = 61440 B (fits 2 blocks/CU in 160 KiB LDS)
    __shared__ float lds[POS_PER_BLOCK * 15];

    const int tid = threadIdx.x;
    const int p0  = (blockIdx.x * BLOCK + tid) * VEC;   // 4 consecutive positions

    if (p0 + VEC <= total) {
        // decompose p0 -> (b, n, s0); all 4 positions share (b, n) since GG % 4 == 0
        int b   = p0 / (NUM * GG);
        int rem = p0 - b * (NUM * GG);
        int n   = rem / GG;
        int s0  = rem - n * GG;

        const float* xp  = x + (size_t)b * (NUM * CPA * GG) + (size_t)(n * CPA) * GG + (size_t)s0;
        const float* xcb = x + (size_t)b * (NUM * CPA * GG) + (size_t)s0;

        // 7 box/conf channels as float4 (16B-aligned: s0 % 4 == 0, GG % 4 == 0)
        float4 t0 = *(const float4*)(xp + 0 * GG);
        float4 t1 = *(const float4*)(xp + 1 * GG);
        float4 t2 = *(const float4*)(xp + 2 * GG);
        float4 t3 = *(const float4*)(xp + 3 * GG);
        float4 im = *(const float4*)(xp + 4 * GG);
        float4 re = *(const float4*)(xp + 5 * GG);
        float4 t6 = *(const float4*)(xp + 6 * GG);

        // 7 scrambled cls channels as float4
        float4 cls[7];
        #pragma unroll
        for (int f = 0; f < 7; ++f) {
            int idx  = 3 * f + n;             // 0..20
            int nsrc = idx / 7;
            int k    = idx - 7 * nsrc;
            cls[f] = *(const float4*)(xcb + (size_t)(nsrc * CPA + 7 + k) * GG);
        }

        const float aw_s = anchors[n * 2 + 0];
        const float ah_s = anchors[n * 2 + 1];

        const float* t0a = &t0.x; const float* t1a = &t1.x;
        const float* t2a = &t2.x; const float* t3a = &t3.x;
        const float* ima = &im.x; const float* rea = &re.x;
        const float* t6a = &t6.x;

        float* base = &lds[tid * (VEC * 15)];

        #pragma unroll
        for (int j = 0; j < VEC; ++j) {
            int s  = s0 + j;
            int gy = s / G;
            int gx = s - gy * G;

            float offx = 1.0f / (1.0f + __expf(-t0a[j]));
            float offy = 1.0f / (1.0f + __expf(-t1a[j]));
            float aw   = __expf(t2a[j]) * aw_s;
            float ah   = __expf(t3a[j]) * ah_s;
            float conf = 1.0f / (1.0f + __expf(-t6a[j]));
            float yaw  = atanf(ima[j] / rea[j]);
            float ax   = floorf((offx + (float)gx) * STRIDE);
            float ay   = floorf((offy + (float)gy) * STRIDE);

            float* v = base + j * 15;
            v[0] = ima[j]; v[1] = rea[j];
            v[2] = yaw;    v[3] = conf;
            v[4] = ax;     v[5] = ay;
            v[6] = aw;     v[7] = ah;
            #pragma unroll
            for (int f = 0; f < 7; ++f) v[8 + f] = (&cls[f].x)[j];
        }
    }

    __syncthreads();

    // coalesced flush: 1024*15 floats = 3840 float4 (15 per thread), no tail
    // (total % POS_PER_BLOCK == 0 for this problem: 4435968 / 1024 = 4332)
    const size_t blockbase = (size_t)blockIdx.x * (POS_PER_BLOCK * 15);
    const size_t out_total = (size_t)total * 15;

    if (blockbase + (size_t)(POS_PER_BLOCK * 15) <= out_total) {
        const float4* l4 = (const float4*)lds;
        float4* o4 = (float4*)(out + blockbase);
        #pragma unroll
        for (int j = tid; j < POS_PER_BLOCK * 15 / 4; j += BLOCK) o4[j] = l4[j];
    } else {
        size_t nrem = out_total > blockbase ? out_total - blockbase : 0;
        for (size_t j = tid; j < nrem; j += BLOCK) out[blockbase + j] = lds[j];
    }
}

extern "C" void kernel_launch(void* const* d_in, const int* in_sizes, int n_in,
                              void* d_out, int out_size, void* d_ws, size_t ws_size,
                              hipStream_t stream) {
    const float* x       = (const float*)d_in[0];
    const float* anchors = (const float*)d_in[1];
    float* out           = (float*)d_out;

    const int total = in_sizes[0] / 14;                      // B*NUM*G*G positions
    const int grid  = (total + POS_PER_BLOCK - 1) / POS_PER_BLOCK;  // 4332

    yolo_decode_kernel<<<grid, BLOCK, 0, stream>>>(x, anchors, out, total);
}

// Round 3
// 86.031 us; speedup vs baseline: 1.1640x; 1.1640x over previous
//
#include <hip/hip_runtime.h>
#include <math.h>

#define BLOCK 256
#define VEC   2
#define PPB   (BLOCK * VEC)   // 512 positions per block

typedef float f32x2 __attribute__((ext_vector_type(2)));
typedef float f32x4 __attribute__((ext_vector_type(4)));

__global__ __launch_bounds__(BLOCK) void yolo_decode_kernel(
    const float* __restrict__ x,
    const float* __restrict__ anchors,
    float* __restrict__ out,
    int total)
{
    constexpr int G   = 152;
    constexpr int GG  = G * G;        // 23104 (even -> VEC=2 pairs never straddle a plane)
    constexpr int NUM = 3;
    constexpr int CPA = 14;
    constexpr float STRIDE = 4.0f;    // 608 / 152

    // 512 pos x 15 floats = 30720 B -> 5 blocks/CU = 20 waves/CU
    __shared__ float lds[PPB * 15];

    const int tid = threadIdx.x;
    const int p0  = (blockIdx.x * BLOCK + tid) * VEC;

    if (p0 + VEC <= total) {
        int b   = p0 / (NUM * GG);
        int rem = p0 - b * (NUM * GG);
        int n   = rem / GG;
        int s0  = rem - n * GG;

        const float* xp  = x + (size_t)b * (NUM * CPA * GG) + (size_t)(n * CPA) * GG + (size_t)s0;
        const float* xcb = x + (size_t)b * (NUM * CPA * GG) + (size_t)s0;

        // 7 box/conf channels, 8 B nontemporal loads (read-once streams)
        f32x2 t0 = __builtin_nontemporal_load((const f32x2*)(xp + 0 * GG));
        f32x2 t1 = __builtin_nontemporal_load((const f32x2*)(xp + 1 * GG));
        f32x2 t2 = __builtin_nontemporal_load((const f32x2*)(xp + 2 * GG));
        f32x2 t3 = __builtin_nontemporal_load((const f32x2*)(xp + 3 * GG));
        f32x2 im = __builtin_nontemporal_load((const f32x2*)(xp + 4 * GG));
        f32x2 re = __builtin_nontemporal_load((const f32x2*)(xp + 5 * GG));
        f32x2 t6 = __builtin_nontemporal_load((const f32x2*)(xp + 6 * GG));

        // 7 scrambled cls channels
        f32x2 cls[7];
        #pragma unroll
        for (int f = 0; f < 7; ++f) {
            int idx  = 3 * f + n;             // 0..20
            int nsrc = idx / 7;
            int k    = idx - 7 * nsrc;
            cls[f] = __builtin_nontemporal_load(
                (const f32x2*)(xcb + (size_t)(nsrc * CPA + 7 + k) * GG));
        }

        const float aw_s = anchors[n * 2 + 0];
        const float ah_s = anchors[n * 2 + 1];

        float* base = &lds[tid * (VEC * 15)];

        #pragma unroll
        for (int j = 0; j < VEC; ++j) {
            int s  = s0 + j;
            int gy = s / G;
            int gx = s - gy * G;

            float offx = 1.0f / (1.0f + __expf(-t0[j]));
            float offy = 1.0f / (1.0f + __expf(-t1[j]));
            float aw   = __expf(t2[j]) * aw_s;
            float ah   = __expf(t3[j]) * ah_s;
            float conf = 1.0f / (1.0f + __expf(-t6[j]));
            float yaw  = atanf(im[j] / re[j]);
            float ax   = floorf((offx + (float)gx) * STRIDE);
            float ay   = floorf((offy + (float)gy) * STRIDE);

            float* v = base + j * 15;
            v[0] = im[j]; v[1] = re[j];
            v[2] = yaw;   v[3] = conf;
            v[4] = ax;    v[5] = ay;
            v[6] = aw;    v[7] = ah;
            #pragma unroll
            for (int f = 0; f < 7; ++f) v[8 + f] = cls[f][j];
        }
    }

    __syncthreads();

    // coalesced nontemporal flush: 512*15 floats = 1920 float4
    const size_t blockbase = (size_t)blockIdx.x * (PPB * 15);
    const size_t out_total = (size_t)total * 15;

    if (blockbase + (size_t)(PPB * 15) <= out_total) {
        const f32x4* l4 = (const f32x4*)lds;     // ds_read_b128, conflict-free
        f32x4* o4 = (f32x4*)(out + blockbase);
        #pragma unroll
        for (int j = tid; j < PPB * 15 / 4; j += BLOCK)
            __builtin_nontemporal_store(l4[j], o4 + j);
    } else {
        size_t nrem = out_total > blockbase ? out_total - blockbase : 0;
        for (size_t j = tid; j < nrem; j += BLOCK) out[blockbase + j] = lds[j];
    }
}

extern "C" void kernel_launch(void* const* d_in, const int* in_sizes, int n_in,
                              void* d_out, int out_size, void* d_ws, size_t ws_size,
                              hipStream_t stream) {
    const float* x       = (const float*)d_in[0];
    const float* anchors = (const float*)d_in[1];
    float* out           = (float*)d_out;

    const int total = in_sizes[0] / 14;              // B*NUM*G*G = 4435968
    const int grid  = (total + PPB - 1) / PPB;       // 8664

    yolo_decode_kernel<<<grid, BLOCK, 0, stream>>>(x, anchors, out, total);
}